// Round 5
// baseline (324.317 us; speedup 1.0000x reference)
//
#include <hip/hip_runtime.h>

typedef float f4 __attribute__((ext_vector_type(4)));

#define EV_G 128           // events per 16-lane group (contiguous, sorted)
#define NG   4             // groups per wave
#define EPW  (EV_G * NG)   // 512 events per wave
#define WPB  4             // waves per block (256 threads)
#define CH   16            // events per chunk (one per sublane)
#define NCH  (EV_G / CH)   // 8 chunks per group

// Zero exactly the rows that receive atomicAdd flushes: first/last target of
// every group's contiguous EV_G-event span. 16 lanes zero one 256 B row (f4).
__global__ __launch_bounds__(256) void prezero_kernel(
    const int* __restrict__ acd0, float* __restrict__ out, int ngroups, int M)
{
    const int task = blockIdx.x * 16 + (threadIdx.x >> 4);
    const int s    = threadIdx.x & 15;
    if (task >= 2 * ngroups) return;
    long m = (long)(task >> 1) * EV_G + ((task & 1) ? (EV_G - 1) : 0);
    if (m >= M) m = M - 1;
    const int t = acd0[m];
    f4 z = {0.f, 0.f, 0.f, 0.f};
    __builtin_nontemporal_store(z, (f4*)(out + (size_t)t * 64 + s * 4));
}

__global__ __launch_bounds__(256, 3) void spspmm_seg_kernel(
    const float* __restrict__ Aval,   // [NNZ_A, 64]
    const float* __restrict__ Bval,   // [NNZ_B]
    const int*   __restrict__ acd0,   // [M] sorted target idx
    const int*   __restrict__ acd1,   // [M] A row idx
    const int*   __restrict__ acd2,   // [M] B idx
    float*       __restrict__ out,    // [TAR, 64]
    int M, int TAR)
{
    const int lane = threadIdx.x & 63;
    const int s    = lane & 15;           // sublane: channels [s*4, s*4+4)
    const int g    = lane >> 4;           // group within wave
    const int wid  = blockIdx.x * WPB + (threadIdx.x >> 6);
    const long gm0 = (long)wid * EPW + (long)g * EV_G;
    if (gm0 >= M) return;
    const long gEnd = (gm0 + EV_G < (long)M) ? gm0 + EV_G : (long)M;
    const int  nev  = (int)(gEnd - gm0);

    const f4 z4 = {0.f, 0.f, 0.f, 0.f};

    const int t_first = acd0[gm0];
    const int t_prev  = (gm0 > 0) ? acd0[gm0 - 1] : -1;
    // Leading gap: targets with no events between prev event's target and ours.
    for (int t = t_prev + 1; t < t_first; ++t)
        __builtin_nontemporal_store(z4, (f4*)(out + (size_t)t * 64 + s * 4));

    f4  acc   = z4;
    int cur_t = t_first;

    auto flush = [&](int next_t) {
        float* p = out + (size_t)cur_t * 64 + s * 4;
        if (cur_t == t_first) {            // span boundary -> atomic (pre-zeroed)
            atomicAdd(p + 0, acc[0]); atomicAdd(p + 1, acc[1]);
            atomicAdd(p + 2, acc[2]); atomicAdd(p + 3, acc[3]);
        } else {                           // group-exclusive interior row
            __builtin_nontemporal_store(acc, (f4*)p);
        }
        for (int tz = cur_t + 1; tz < next_t; ++tz)   // interior empty rows
            __builtin_nontemporal_store(z4, (f4*)(out + (size_t)tz * 64 + s * 4));
        acc   = z4;
        cur_t = next_t;
    };

    // Descriptor load for chunk c: lane s holds event gm0 + c*CH + s.
    auto desc = [&](int c, int &t, int &a, float &b) {
        const long mb = gm0 + (long)c * CH + s;
        t = __builtin_nontemporal_load(acd0 + mb);
        a = __builtin_nontemporal_load(acd1 + mb);
        b = Bval[__builtin_nontemporal_load(acd2 + mb)];
    };
    // Issue all 16 A-row gathers of a chunk back-to-back (1 KB / instruction).
    auto gather = [&](f4 (&v)[CH], int a_i) {
        #pragma unroll
        for (int j = 0; j < CH; ++j) {
            const int a = __shfl(a_i, j, 16);
            v[j] = *(const f4*)(Aval + (size_t)a * 64 + s * 4);
        }
    };
    // Segment scan of one chunk (group-uniform control flow).
    auto scan = [&](const f4 (&v)[CH], int t_i, float b_i) {
        #pragma unroll
        for (int j = 0; j < CH; ++j) {
            const int   t  = __shfl(t_i, j, 16);
            const float bv = __shfl(b_i, j, 16);
            if (t != cur_t) flush(t);
            acc += v[j] * bv;
        }
    };

    if (nev == EV_G) {
        int tA, aA, tB, aB; float bA, bB;
        f4 vA[CH], vB[CH];
        // Software pipeline: chunk c+1's loads are in flight while scanning c.
        desc(0, tA, aA, bA); gather(vA, aA);
        #pragma unroll 1
        for (int c = 0; c < NCH; c += 2) {
            desc(c + 1, tB, aB, bB); gather(vB, aB);
            scan(vA, tA, bA);
            if (c + 2 < NCH) { desc(c + 2, tA, aA, bA); gather(vA, aA); }
            scan(vB, tB, bB);
        }
    } else {
        // Tail span (not hit when M % EPW == 0): per-event broadcast loads.
        for (int m = 0; m < nev; ++m) {
            const int   t  = acd0[gm0 + m];
            const int   a  = acd1[gm0 + m];
            const float bv = Bval[acd2[gm0 + m]];
            const f4    v  = *(const f4*)(Aval + (size_t)a * 64 + s * 4);
            if (t != cur_t) flush(t);
            acc += v * bv;
        }
    }

    // Final segment may continue into the next group -> atomic (pre-zeroed).
    {
        float* p = out + (size_t)cur_t * 64 + s * 4;
        atomicAdd(p + 0, acc[0]); atomicAdd(p + 1, acc[1]);
        atomicAdd(p + 2, acc[2]); atomicAdd(p + 3, acc[3]);
    }

    // Trailing gap after the very last event's target.
    if (gEnd == M) {
        const int tl = acd0[M - 1];
        for (int t = tl + 1; t < TAR; ++t)
            __builtin_nontemporal_store(z4, (f4*)(out + (size_t)t * 64 + s * 4));
    }
}

extern "C" void kernel_launch(void* const* d_in, const int* in_sizes, int n_in,
                              void* d_out, int out_size, void* d_ws, size_t ws_size,
                              hipStream_t stream) {
    const float* Aval = (const float*)d_in[0];
    const float* Bval = (const float*)d_in[1];
    const int*   acd0 = (const int*)d_in[2];
    const int*   acd1 = (const int*)d_in[3];
    const int*   acd2 = (const int*)d_in[4];
    float* out = (float*)d_out;
    const int M   = in_sizes[2];
    const int TAR = out_size / 64;

    const int ngroups = (M + EV_G - 1) / EV_G;

    // Pre-zero only the atomic-target rows (~16 MB instead of 256 MB memset).
    {
        const int tasks  = 2 * ngroups;
        const int blocks = (tasks + 15) / 16;
        prezero_kernel<<<dim3(blocks), dim3(256), 0, stream>>>(acd0, out, ngroups, M);
    }

    const long nwaves = ((long)M + EPW - 1) / EPW;
    const long blocks = (nwaves + WPB - 1) / WPB;
    spspmm_seg_kernel<<<dim3((unsigned)blocks), dim3(WPB * 64), 0, stream>>>(
        Aval, Bval, acd0, acd1, acd2, out, M, TAR);
}

// Round 6
// 280.225 us; speedup vs baseline: 1.1573x; 1.1573x over previous
//
#include <hip/hip_runtime.h>

typedef float          f4    __attribute__((ext_vector_type(4)));
typedef unsigned short u16x4 __attribute__((ext_vector_type(4)));

#define EV_G 64            // events per 16-lane group (contiguous, sorted)
#define NG   4             // groups per wave
#define EPW  (EV_G * NG)   // 256 events per wave
#define WPB  4             // waves per block (256 threads)
#define CH   16            // events per chunk (one per sublane)

__device__ __forceinline__ unsigned short f2bf(float f) {
    unsigned u = __float_as_uint(f);
    return (unsigned short)((u + 0x7fffu + ((u >> 16) & 1u)) >> 16);   // RNE
}
__device__ __forceinline__ f4 tofloat(f4 v) { return v; }
__device__ __forceinline__ f4 tofloat(u16x4 u) {
    f4 r;
    r[0] = __uint_as_float((unsigned)u[0] << 16);
    r[1] = __uint_as_float((unsigned)u[1] << 16);
    r[2] = __uint_as_float((unsigned)u[2] << 16);
    r[3] = __uint_as_float((unsigned)u[3] << 16);
    return r;
}

// Aval f32 -> bf16 table in d_ws (128 MB: fits in half of Infinity Cache).
__global__ __launch_bounds__(256) void conv_kernel(
    const float* __restrict__ A, unsigned short* __restrict__ Abf, long n4)
{
    long i = (long)blockIdx.x * 256 + threadIdx.x;
    const long stride = (long)gridDim.x * 256;
    for (; i < n4; i += stride) {
        f4 v = __builtin_nontemporal_load(((const f4*)A) + i);
        u16x4 o;
        o[0] = f2bf(v[0]); o[1] = f2bf(v[1]); o[2] = f2bf(v[2]); o[3] = f2bf(v[3]);
        ((u16x4*)Abf)[i] = o;   // normal store: allocate in caches
    }
}

// Zero exactly the rows that receive atomicAdds: targets shared across a
// group boundary (acd0[w*EV_G-1] == acd0[w*EV_G]). 16 lanes zero one row.
__global__ __launch_bounds__(256) void prezero_kernel(
    const int* __restrict__ acd0, float* __restrict__ out, int ngroups, int M)
{
    const int task = blockIdx.x * 16 + (threadIdx.x >> 4);
    const int s    = threadIdx.x & 15;
    if (task < 1 || task >= ngroups) return;
    const long m = (long)task * EV_G;
    if (m >= M) return;
    const int t = acd0[m];
    if (acd0[m - 1] != t) return;            // boundary not shared -> no atomics
    f4 z = {0.f, 0.f, 0.f, 0.f};
    __builtin_nontemporal_store(z, (f4*)(out + (size_t)t * 64 + s * 4));
}

template <typename AT>   // AT = unsigned short (bf16 table) or float (fallback)
__global__ __launch_bounds__(256, 4) void spspmm_seg_kernel(
    const AT*    __restrict__ Aval,   // [NNZ_A, 64]
    const float* __restrict__ Bval,   // [NNZ_B]
    const int*   __restrict__ acd0,   // [M] sorted target idx
    const int*   __restrict__ acd1,   // [M] A row idx
    const int*   __restrict__ acd2,   // [M] B idx
    float*       __restrict__ out,    // [TAR, 64]
    int M, int TAR)
{
    typedef __attribute__((ext_vector_type(4)))
        typename std::conditional<sizeof(AT) == 2, unsigned short, float>::type VecT;

    const int lane = threadIdx.x & 63;
    const int s    = lane & 15;           // sublane: channels [s*4, s*4+4)
    const int g    = lane >> 4;           // group within wave
    const int wid  = blockIdx.x * WPB + (threadIdx.x >> 6);
    const long gm0 = (long)wid * EPW + (long)g * EV_G;
    if (gm0 >= M) return;
    const long gEnd = (gm0 + EV_G < (long)M) ? gm0 + EV_G : (long)M;
    const int  nev  = (int)(gEnd - gm0);

    const f4 z4 = {0.f, 0.f, 0.f, 0.f};

    const int t_first = acd0[gm0];
    const int t_prev  = (gm0 > 0)   ? acd0[gm0 - 1] : -1;
    const int t_next  = (gEnd < M)  ? acd0[gEnd]    : -1;

    // Leading gap: targets with no events between prev event's target and ours.
    for (int t = t_prev + 1; t < t_first; ++t)
        __builtin_nontemporal_store(z4, (f4*)(out + (size_t)t * 64 + s * 4));

    f4  acc   = z4;
    int cur_t = t_first;

    auto store_acc = [&](bool shared) {
        float* p = out + (size_t)cur_t * 64 + s * 4;
        if (shared) {                      // crosses a group boundary (pre-zeroed)
            atomicAdd(p + 0, acc[0]); atomicAdd(p + 1, acc[1]);
            atomicAdd(p + 2, acc[2]); atomicAdd(p + 3, acc[3]);
        } else {                           // group-exclusive row
            __builtin_nontemporal_store(acc, (f4*)p);
        }
    };
    auto flush = [&](int next_t) {
        store_acc(cur_t == t_first && cur_t == t_prev);
        for (int tz = cur_t + 1; tz < next_t; ++tz)   // interior empty rows
            __builtin_nontemporal_store(z4, (f4*)(out + (size_t)tz * 64 + s * 4));
        acc   = z4;
        cur_t = next_t;
    };

    if (nev == EV_G) {
        #pragma unroll 1
        for (int c = 0; c < EV_G / CH; ++c) {
            const long mb = gm0 + (long)c * CH;
            // Coalesced descriptor load: lane s holds event mb+s of its group.
            const int   t_i = __builtin_nontemporal_load(acd0 + mb + s);
            const int   a_i = __builtin_nontemporal_load(acd1 + mb + s);
            const float b_i = Bval[__builtin_nontemporal_load(acd2 + mb + s)];
            // 16 row gathers batched back-to-back, raw bits (convert later).
            VecT v[CH];
            #pragma unroll
            for (int j = 0; j < CH; ++j) {
                const int a = __shfl(a_i, j, 16);
                v[j] = *(const VecT*)(Aval + (size_t)a * 64 + s * 4);
            }
            // Segment scan (group-uniform control flow).
            #pragma unroll
            for (int j = 0; j < CH; ++j) {
                const int   t  = __shfl(t_i, j, 16);
                const float bv = __shfl(b_i, j, 16);
                if (t != cur_t) flush(t);
                acc += tofloat(v[j]) * bv;
            }
        }
    } else {
        // Tail span (not hit when M % EPW == 0): per-event broadcast loads.
        for (int m = 0; m < nev; ++m) {
            const int   t  = acd0[gm0 + m];
            const int   a  = acd1[gm0 + m];
            const float bv = Bval[acd2[gm0 + m]];
            const VecT  v  = *(const VecT*)(Aval + (size_t)a * 64 + s * 4);
            if (t != cur_t) flush(t);
            acc += tofloat(v) * bv;
        }
    }

    // Final segment: shared iff it continues into the next group, or it is the
    // whole-group segment continuing from the previous group.
    store_acc((cur_t == t_next) || (cur_t == t_first && cur_t == t_prev));

    // Trailing gap after the very last event's target.
    if (gEnd == M) {
        const int tl = acd0[M - 1];
        for (int t = tl + 1; t < TAR; ++t)
            __builtin_nontemporal_store(z4, (f4*)(out + (size_t)t * 64 + s * 4));
    }
}

extern "C" void kernel_launch(void* const* d_in, const int* in_sizes, int n_in,
                              void* d_out, int out_size, void* d_ws, size_t ws_size,
                              hipStream_t stream) {
    const float* Aval = (const float*)d_in[0];
    const float* Bval = (const float*)d_in[1];
    const int*   acd0 = (const int*)d_in[2];
    const int*   acd1 = (const int*)d_in[3];
    const int*   acd2 = (const int*)d_in[4];
    float* out = (float*)d_out;
    const int M   = in_sizes[2];
    const int TAR = out_size / 64;
    const long nA_elems = in_sizes[0];          // NNZ_A * 64

    const int ngroups = (M + EV_G - 1) / EV_G;

    // Pre-zero only the shared-boundary (atomic-target) rows.
    {
        const int blocks = (ngroups + 15) / 16;
        prezero_kernel<<<dim3(blocks), dim3(256), 0, stream>>>(acd0, out, ngroups, M);
    }

    const long nwaves = ((long)M + EPW - 1) / EPW;
    const long blocks = (nwaves + WPB - 1) / WPB;

    if (ws_size >= (size_t)nA_elems * 2) {
        // bf16 A table in scratch: halves gather bytes, fits in half of L3.
        unsigned short* Abf = (unsigned short*)d_ws;
        conv_kernel<<<dim3(2048), dim3(256), 0, stream>>>(Aval, Abf, nA_elems / 4);
        spspmm_seg_kernel<unsigned short><<<dim3((unsigned)blocks), dim3(WPB * 64), 0, stream>>>(
            Abf, Bval, acd0, acd1, acd2, out, M, TAR);
    } else {
        spspmm_seg_kernel<float><<<dim3((unsigned)blocks), dim3(WPB * 64), 0, stream>>>(
            Aval, Bval, acd0, acd1, acd2, out, M, TAR);
    }
}

// Round 7
// 278.953 us; speedup vs baseline: 1.1626x; 1.0046x over previous
//
#include <hip/hip_runtime.h>

typedef float          f4    __attribute__((ext_vector_type(4)));
typedef unsigned short u16x4 __attribute__((ext_vector_type(4)));

#define EV_G 64            // events per 16-lane group (contiguous, sorted)
#define NG   4             // groups per wave
#define EPW  (EV_G * NG)   // 256 events per wave
#define WPB  4             // waves per block (256 threads)
#define CH   16            // events per chunk (one per sublane)

__device__ __forceinline__ unsigned short f2bf(float f) {
    unsigned u = __float_as_uint(f);
    return (unsigned short)((u + 0x7fffu + ((u >> 16) & 1u)) >> 16);   // RNE
}
__device__ __forceinline__ f4 tofloat(u16x4 u) {
    f4 r;
    r[0] = __uint_as_float((unsigned)u[0] << 16);
    r[1] = __uint_as_float((unsigned)u[1] << 16);
    r[2] = __uint_as_float((unsigned)u[2] << 16);
    r[3] = __uint_as_float((unsigned)u[3] << 16);
    return r;
}

// Device-scope non-temporal store: bypass L2 allocation (sc1) and mark
// no-allocate (nt) so the out-stream does not evict the bf16 A table / Bval.
__device__ __forceinline__ void nt_store_f4(float* p, f4 v) {
    asm volatile("global_store_dwordx4 %0, %1, off sc1 nt"
                 :: "v"(p), "v"(v) : "memory");
}

// Aval f32 -> bf16 table in d_ws (128 MB). The f32 read is a one-shot stream:
// sc1 nt so it does not wipe L3 (which we want holding the bf16 table).
__global__ __launch_bounds__(256) void conv_kernel(
    const float* __restrict__ A, unsigned short* __restrict__ Abf, long n4)
{
    long i = (long)blockIdx.x * 256 + threadIdx.x;
    const long stride = (long)gridDim.x * 256;
    for (; i < n4; i += stride) {
        f4 v;
        const float* p = (const float*)(((const f4*)A) + i);
        asm volatile("global_load_dwordx4 %0, %1, off sc1 nt\n\ts_waitcnt vmcnt(0)"
                     : "=v"(v) : "v"(p) : "memory");
        u16x4 o;
        o[0] = f2bf(v[0]); o[1] = f2bf(v[1]); o[2] = f2bf(v[2]); o[3] = f2bf(v[3]);
        ((u16x4*)Abf)[i] = o;   // normal store: allocate table in caches
    }
}

// Zero exactly the rows that receive atomicAdds: targets shared across a
// group boundary (acd0[w*EV_G-1] == acd0[w*EV_G]). 16 lanes zero one row.
__global__ __launch_bounds__(256) void prezero_kernel(
    const int* __restrict__ acd0, float* __restrict__ out, int ngroups, int M)
{
    const int task = blockIdx.x * 16 + (threadIdx.x >> 4);
    const int s    = threadIdx.x & 15;
    if (task < 1 || task >= ngroups) return;
    const long m = (long)task * EV_G;
    if (m >= M) return;
    const int t = acd0[m];
    if (acd0[m - 1] != t) return;            // boundary not shared -> no atomics
    f4 z = {0.f, 0.f, 0.f, 0.f};
    nt_store_f4(out + (size_t)t * 64 + s * 4, z);
}

__global__ __launch_bounds__(256, 4) void spspmm_seg_kernel(
    const unsigned short* __restrict__ Aval,   // [NNZ_A, 64] bf16 bits
    const float* __restrict__ Bval,   // [NNZ_B]
    const int*   __restrict__ acd0,   // [M] sorted target idx
    const int*   __restrict__ acd1,   // [M] A row idx
    const int*   __restrict__ acd2,   // [M] B idx
    float*       __restrict__ out,    // [TAR, 64]
    int M, int TAR)
{
    const int lane = threadIdx.x & 63;
    const int s    = lane & 15;           // sublane: channels [s*4, s*4+4)
    const int g    = lane >> 4;           // group within wave
    const int wid  = blockIdx.x * WPB + (threadIdx.x >> 6);
    const long gm0 = (long)wid * EPW + (long)g * EV_G;
    if (gm0 >= M) return;
    const long gEnd = (gm0 + EV_G < (long)M) ? gm0 + EV_G : (long)M;
    const int  nev  = (int)(gEnd - gm0);

    const f4 z4 = {0.f, 0.f, 0.f, 0.f};

    const int t_first = acd0[gm0];
    const int t_prev  = (gm0 > 0)   ? acd0[gm0 - 1] : -1;
    const int t_next  = (gEnd < M)  ? acd0[gEnd]    : -1;

    // Leading gap: targets with no events between prev event's target and ours.
    for (int t = t_prev + 1; t < t_first; ++t)
        nt_store_f4(out + (size_t)t * 64 + s * 4, z4);

    f4  acc   = z4;
    int cur_t = t_first;

    auto store_acc = [&](bool shared) {
        float* p = out + (size_t)cur_t * 64 + s * 4;
        if (shared) {                      // crosses a group boundary (pre-zeroed)
            atomicAdd(p + 0, acc[0]); atomicAdd(p + 1, acc[1]);
            atomicAdd(p + 2, acc[2]); atomicAdd(p + 3, acc[3]);
        } else {                           // group-exclusive row
            nt_store_f4(p, acc);
        }
    };
    auto flush = [&](int next_t) {
        store_acc(cur_t == t_first && cur_t == t_prev);
        for (int tz = cur_t + 1; tz < next_t; ++tz)   // interior empty rows
            nt_store_f4(out + (size_t)tz * 64 + s * 4, z4);
        acc   = z4;
        cur_t = next_t;
    };

    if (nev == EV_G) {
        #pragma unroll 1
        for (int c = 0; c < EV_G / CH; ++c) {
            const long mb = gm0 + (long)c * CH;
            // Coalesced descriptor load: lane s holds event mb+s of its group.
            const int   t_i = __builtin_nontemporal_load(acd0 + mb + s);
            const int   a_i = __builtin_nontemporal_load(acd1 + mb + s);
            const float b_i = Bval[__builtin_nontemporal_load(acd2 + mb + s)];
            // 16 row gathers batched back-to-back, raw bf16 bits.
            u16x4 v[CH];
            #pragma unroll
            for (int j = 0; j < CH; ++j) {
                const int a = __shfl(a_i, j, 16);
                v[j] = *(const u16x4*)(Aval + (size_t)a * 64 + s * 4);
            }
            // Segment scan (group-uniform control flow).
            #pragma unroll
            for (int j = 0; j < CH; ++j) {
                const int   t  = __shfl(t_i, j, 16);
                const float bv = __shfl(b_i, j, 16);
                if (t != cur_t) flush(t);
                acc += tofloat(v[j]) * bv;
            }
        }
    } else {
        // Tail span (not hit when M % EPW == 0): per-event broadcast loads.
        for (int m = 0; m < nev; ++m) {
            const int   t  = acd0[gm0 + m];
            const int   a  = acd1[gm0 + m];
            const float bv = Bval[acd2[gm0 + m]];
            const u16x4 v  = *(const u16x4*)(Aval + (size_t)a * 64 + s * 4);
            if (t != cur_t) flush(t);
            acc += tofloat(v) * bv;
        }
    }

    // Final segment: shared iff it continues into the next group, or it is the
    // whole-group segment continuing from the previous group.
    store_acc((cur_t == t_next) || (cur_t == t_first && cur_t == t_prev));

    // Trailing gap after the very last event's target.
    if (gEnd == M) {
        const int tl = acd0[M - 1];
        for (int t = tl + 1; t < TAR; ++t)
            nt_store_f4(out + (size_t)t * 64 + s * 4, z4);
    }
}

extern "C" void kernel_launch(void* const* d_in, const int* in_sizes, int n_in,
                              void* d_out, int out_size, void* d_ws, size_t ws_size,
                              hipStream_t stream) {
    const float* Aval = (const float*)d_in[0];
    const float* Bval = (const float*)d_in[1];
    const int*   acd0 = (const int*)d_in[2];
    const int*   acd1 = (const int*)d_in[3];
    const int*   acd2 = (const int*)d_in[4];
    float* out = (float*)d_out;
    const int M   = in_sizes[2];
    const int TAR = out_size / 64;
    const long nA_elems = in_sizes[0];          // NNZ_A * 64

    const int ngroups = (M + EV_G - 1) / EV_G;

    // Pre-zero only the shared-boundary (atomic-target) rows.
    {
        const int blocks = (ngroups + 15) / 16;
        prezero_kernel<<<dim3(blocks), dim3(256), 0, stream>>>(acd0, out, ngroups, M);
    }

    // bf16 A table in scratch: halves gather bytes, meant to live in L3.
    unsigned short* Abf = (unsigned short*)d_ws;
    conv_kernel<<<dim3(2048), dim3(256), 0, stream>>>(Aval, Abf, nA_elems / 4);

    const long nwaves = ((long)M + EPW - 1) / EPW;
    const long blocks = (nwaves + WPB - 1) / WPB;
    spspmm_seg_kernel<<<dim3((unsigned)blocks), dim3(WPB * 64), 0, stream>>>(
        Abf, Bval, acd0, acd1, acd2, out, M, TAR);
}